// Round 10
// baseline (409.603 us; speedup 1.0000x reference)
//
#include <hip/hip_runtime.h>

// Problem constants (match reference)
#define TT 20      // timesteps
#define GG 1024    // groups
#define PP 64      // pedestrians per group
#define THR 0.25f

typedef float f32x4 __attribute__((ext_vector_type(4)));

// LDS-only barrier (no vmcnt drain)
#define BARRIER_LDS() asm volatile("s_waitcnt lgkmcnt(0)\n\ts_barrier" ::: "memory")

// R10: ZERO-STREAM + SPARSE FIXUP.
// Inputs are N(0,1): per-coord pair diffs are N(0,2), so
// P(dist < 0.25) ~ 1.5% -> ~98.5% of the 335 MB output is exactly 0.
// Phase 1: each wave nt-stores zeros over its whole output slice
//   (8 rows x 5 KB, 40 back-to-back dwordx4 stores, NO data dependency —
//   structurally identical to the 6.24 TB/s rocclr fill).
// Sync:    one per-wave s_waitcnt vmcnt(0), overlapped with row-0 compute.
// Phase 2: per row, compute 20 costs in regs (readlane broadcast of xi);
//   per t, whole-wave skip via __any, else exec-masked scalar nt store of
//   the ~1 nonzero lane. No LDS transpose at all (DS = staging only).
// Ordering: fixup and zero hit the same address only within one wave,
// separated by the vmcnt(0) drain -> well-ordered.
__global__ __launch_bounds__(256) void traj_critic_kernel(
    const float* __restrict__ traj, float* __restrict__ out)
{
    __shared__ float4 xsb[640];   // 10240 B staging: [t][p] float2

    const int blk  = blockIdx.x;
    const int g    = blk >> 1;
    const int half = blk & 1;
    const int tid  = threadIdx.x;
    const int lane = tid & 63;
    const int wid  = tid >> 6;

    // ---- stage group's (T,P,2) f32 -> LDS ----
    {
        const float4* tg = (const float4*)traj;
        for (int u = tid; u < 640; u += 256) {
            int t = u >> 5;
            int r = u & 31;
            xsb[u] = tg[t * 32768 + g * 32 + r];
        }
    }
    BARRIER_LDS();

    // per-lane trajectory of ped j = lane (40 VGPRs)
    float2 xj[TT];
    const float2* xs2 = (const float2*)xsb;
#pragma unroll
    for (int t = 0; t < TT; ++t) xj[t] = xs2[t * 64 + lane];

    float* outf = out + (size_t)g * (PP * PP * TT);
    f32x4* outg4 = (f32x4*)outf;

    // ---- phase 1: dependency-free zero stream over this wave's slice ----
    const f32x4 zr = { 0.0f, 0.0f, 0.0f, 0.0f };
#pragma unroll
    for (int c = 0; c < 8; ++c) {
        const int i = half * 32 + c * 4 + wid;
        f32x4* op = outg4 + (size_t)i * 320;
#pragma unroll
        for (int k = 0; k < 5; ++k)
            __builtin_nontemporal_store(zr, &op[k * 64 + lane]);
    }

    float cst[TT];

#define COMPUTE_ROW(IVAR)                                                     \
    {                                                                         \
        const float kill = ((IVAR) == lane) ? 0.0f : 1.0f;                    \
        _Pragma("unroll")                                                     \
        for (int t = 0; t < TT; ++t) {                                        \
            float xix = __int_as_float(                                       \
                __builtin_amdgcn_readlane(__float_as_int(xj[t].x), (IVAR)));  \
            float xiy = __int_as_float(                                       \
                __builtin_amdgcn_readlane(__float_as_int(xj[t].y), (IVAR)));  \
            float dx = xix - xj[t].x;                                         \
            float dy = xiy - xj[t].y;                                         \
            float d  = __builtin_amdgcn_sqrtf(dx * dx + dy * dy);             \
            float v  = THR - d;                                               \
            v = v > 0.0f ? v : 0.0f;                                          \
            cst[t] = v * kill;                                                \
        }                                                                     \
    }

#define FIXUP_ROW(IVAR)                                                       \
    {                                                                         \
        float* rp = outf + (size_t)((IVAR) * 64 + lane) * TT;                 \
        _Pragma("unroll")                                                     \
        for (int t = 0; t < TT; ++t) {                                        \
            float cv = cst[t];                                                \
            if (__any(cv > 0.0f)) {                                           \
                if (cv > 0.0f) __builtin_nontemporal_store(cv, rp + t);       \
            }                                                                 \
        }                                                                     \
    }

    // row 0: compute overlaps the zero-stream drain, then one wait
    {
        const int i0r = half * 32 + wid;
        COMPUTE_ROW(i0r);
        asm volatile("s_waitcnt vmcnt(0)" ::: "memory");
        FIXUP_ROW(i0r);
    }
#pragma unroll 1
    for (int c = 1; c < 8; ++c) {
        const int i = half * 32 + c * 4 + wid;
        COMPUTE_ROW(i);
        FIXUP_ROW(i);
    }
#undef COMPUTE_ROW
#undef FIXUP_ROW
}

extern "C" void kernel_launch(void* const* d_in, const int* in_sizes, int n_in,
                              void* d_out, int out_size, void* d_ws, size_t ws_size,
                              hipStream_t stream) {
    const float* traj = (const float*)d_in[0];  // (T, B, 2) f32
    float* out = (float*)d_out;                 // G*P*P*T f32
    traj_critic_kernel<<<2 * GG, 256, 0, stream>>>(traj, out);
}

// Round 11
// 347.642 us; speedup vs baseline: 1.1782x; 1.1782x over previous
//
#include <hip/hip_runtime.h>

// Problem constants (match reference)
#define TT 20      // timesteps
#define GG 1024    // groups
#define PP 64      // pedestrians per group
#define THR 0.25f

// native clang vector (HIP's float4 is a class; the nontemporal builtin
// requires a scalar/native-vector type)
typedef float f32x4 __attribute__((ext_vector_type(4)));

// LDS-only barrier (no vmcnt drain). Only 2 per block, around staging.
#define BARRIER_LDS() asm volatile("s_waitcnt lgkmcnt(0)\n\ts_barrier" ::: "memory")

// FINAL (revert to R8, best measured = 348.3 us bench, ~75 us kernel):
// grid = 2*GG blocks, 256 threads; block does half a group (32 i-rows),
// wave w owns rows i = half*32 + c*4 + w, c = 0..7. Wave-private main loop
// (no barriers): lane l holds ped l's trajectory in regs; xi via readlane
// (SGPR broadcast); swizzled in-LDS transpose (pi(m)=(m&~7)|((5m)&7), both
// sides conflict-free b128); lane-contiguous 1KB nontemporal wave stores.
//
// Experiments R3-R10 on the ~20us gap to the pure-fill rate (6.3 TB/s):
// barrier removal, occupancy, intra-wave SW pipelining, nt stores (+3us,
// kept), XCD-bijective write locality with all blocks co-resident, and a
// zero-stream+sparse-fixup (regression) -- all null. Sustained mixed-op
// store drain for this shape is ~4.6 TB/s; treat as practical roofline.
__global__ __launch_bounds__(256) void traj_critic_kernel(
    const float* __restrict__ traj, float* __restrict__ out)
{
    __shared__ float4 buf[1280];   // 20480 B; first 640 double as staging

    const int blk  = blockIdx.x;
    const int g    = blk >> 1;
    const int half = blk & 1;
    const int tid  = threadIdx.x;
    const int lane = tid & 63;
    const int wid  = tid >> 6;

    // ---- stage group's (T,P,2) f32 -> LDS, layout [t][p] float2 ----
    {
        const float4* tg = (const float4*)traj;
        for (int u = tid; u < 640; u += 256) {
            int t = u >> 5;            // 32 float4 per timestep row
            int r = u & 31;
            buf[u] = tg[t * 32768 + g * 32 + r];
        }
    }
    BARRIER_LDS();

    // per-lane trajectory of ped j = lane (40 VGPRs)
    float2 xj[TT];
    const float2* xs2 = (const float2*)buf;
#pragma unroll
    for (int t = 0; t < TT; ++t) xj[t] = xs2[t * 64 + lane];
    BARRIER_LDS();   // all waves done reading staging before buf overwrite

    const int wbase = wid * 320;                    // wave-private float4 slice
    f32x4* outg4 = (f32x4*)out + (size_t)g * 20480;

#pragma unroll 1
    for (int c = 0; c < 8; ++c) {
        const int i = half * 32 + c * 4 + wid;      // this wave's row
        const float kill = (i == lane) ? 0.0f : 1.0f;

        float cst[TT];
#pragma unroll
        for (int t = 0; t < TT; ++t) {
            float xix = __int_as_float(
                __builtin_amdgcn_readlane(__float_as_int(xj[t].x), i));
            float xiy = __int_as_float(
                __builtin_amdgcn_readlane(__float_as_int(xj[t].y), i));
            float dx = xix - xj[t].x;
            float dy = xiy - xj[t].y;
            float d  = __builtin_amdgcn_sqrtf(dx * dx + dy * dy);
            float v  = THR - d;
            v = v > 0.0f ? v : 0.0f;
            cst[t] = v * kill;                      // diagonal -> 0
        }

        // swizzled wave-private transpose: 5x ds_write_b128, conflict-free
#pragma unroll
        for (int kt = 0; kt < 5; ++kt) {
            int m  = wbase + 5 * lane + kt;
            int pm = (m & ~7) | ((5 * m) & 7);
            buf[pm] = make_float4(cst[4 * kt + 0], cst[4 * kt + 1],
                                  cst[4 * kt + 2], cst[4 * kt + 3]);
        }

        // same-wave read-back + NONTEMPORAL lane-contiguous stores
        f32x4* op = outg4 + (size_t)i * 320;
#pragma unroll
        for (int k = 0; k < 5; ++k) {
            int m  = wbase + k * 64 + lane;
            int pm = (m & ~7) | ((5 * m) & 7);
            float4 v = buf[pm];
            f32x4 nv = { v.x, v.y, v.z, v.w };
            __builtin_nontemporal_store(nv, &op[k * 64 + lane]);
        }
    }
}

extern "C" void kernel_launch(void* const* d_in, const int* in_sizes, int n_in,
                              void* d_out, int out_size, void* d_ws, size_t ws_size,
                              hipStream_t stream) {
    const float* traj = (const float*)d_in[0];  // (T, B, 2) f32
    float* out = (float*)d_out;                 // G*P*P*T f32
    traj_critic_kernel<<<2 * GG, 256, 0, stream>>>(traj, out);
}